// Round 4
// baseline (1552.381 us; speedup 1.0000x reference)
//
#include <hip/hip_runtime.h>

#define H_ 128
#define W_ 128
#define CO_ 64
#define COA_ 63
#define HW_ 16384

// ---------------------------------------------------------------------------
// Weight transpose: w[co][ci][ky][kx] (co<63) -> wt[ky][cib][kx][ci(32)][co(64)]
// co = 63 is zero-padded so the conv kernel can treat Cout as 64 uniformly.
// ---------------------------------------------------------------------------
__global__ __launch_bounds__(256) void prep_weights(
    const float* __restrict__ w, float* __restrict__ wt, int CIN, int KS)
{
    int nblk = CIN >> 5;
    int total = KS * nblk * KS * 32 * 64;
    for (int i = blockIdx.x * 256 + threadIdx.x; i < total; i += gridDim.x * 256) {
        int co = i & 63;
        int r = i >> 6;
        int ci = r & 31; r >>= 5;
        int kx = r % KS; r /= KS;
        int cb = r % nblk;
        int ky = r / nblk;
        int cig = cb * 32 + ci;
        float v = 0.f;
        if (co < COA_)
            v = w[((co * CIN + cig) * KS + ky) * KS + kx];
        wt[i] = v;
    }
}

// ---------------------------------------------------------------------------
// Direct conv (stride 1), one block per (batch, output row).
// Tile: 64 out-channels x 128 pixels. Thread = 8 co x 4 px register block.
// Also accumulates per-channel sum / sumsq (for BN) via block-reduced atomics.
// Output layout: [B][64][H][W] (channel 63 is zero-weight garbage, unused).
// ---------------------------------------------------------------------------
template<int CIN, int KS, int PAD>
__global__ __launch_bounds__(256) void conv_bnstat(
    const float* __restrict__ x, const float* __restrict__ wt,
    const float* __restrict__ bias, float* __restrict__ out,
    float* __restrict__ sums)   // sums[0..63]=sum, sums[64..127]=sumsq
{
    constexpr int XW = W_ + 2 * PAD;
    constexpr int NCB = CIN / 32;
    __shared__ float xs[32][132];
    __shared__ float wl[KS * 32 * 64];

    const int b = blockIdx.x >> 7;
    const int y = blockIdx.x & 127;
    const int t = threadIdx.x;
    const int pg = t & 31;     // pixel group: pixels 4*pg .. 4*pg+3
    const int cgi = t >> 5;    // co group:    co 8*cgi .. 8*cgi+7
    const int px0 = pg << 2;
    const int co0 = cgi << 3;

    float acc[8][4];
    #pragma unroll
    for (int i = 0; i < 8; ++i)
        #pragma unroll
        for (int j = 0; j < 4; ++j) acc[i][j] = 0.f;

    for (int cb = 0; cb < NCB; ++cb) {
        for (int ky = 0; ky < KS; ++ky) {
            __syncthreads();
            const int yy = y + ky - PAD;
            if (yy >= 0 && yy < H_) {
                const float* xrow = x + (((size_t)b * CIN + cb * 32) * H_ + yy) * W_;
                for (int i = t; i < 32 * XW; i += 256) {
                    int ci = i / XW, col = i - ci * XW;
                    int gc = col - PAD;
                    xs[ci][col] = (gc >= 0 && gc < W_) ? xrow[ci * HW_ + gc] : 0.f;
                }
            } else {
                for (int i = t; i < 32 * XW; i += 256) {
                    int ci = i / XW, col = i - ci * XW;
                    xs[ci][col] = 0.f;
                }
            }
            const float* wsrc = wt + (size_t)(ky * NCB + cb) * (KS * 32 * 64);
            for (int i = t; i < KS * 32 * 64; i += 256) wl[i] = wsrc[i];
            __syncthreads();

            #pragma unroll 2
            for (int ci = 0; ci < 32; ++ci) {
                float xv[3 + KS];
                const float4 x4 = *reinterpret_cast<const float4*>(&xs[ci][px0]);
                xv[0] = x4.x; xv[1] = x4.y; xv[2] = x4.z; xv[3] = x4.w;
                #pragma unroll
                for (int j = 4; j < 3 + KS; ++j) xv[j] = xs[ci][px0 + j];
                #pragma unroll
                for (int kx = 0; kx < KS; ++kx) {
                    const float4 wa = *reinterpret_cast<const float4*>(&wl[(kx * 32 + ci) * 64 + co0]);
                    const float4 wb = *reinterpret_cast<const float4*>(&wl[(kx * 32 + ci) * 64 + co0 + 4]);
                    float wv[8] = {wa.x, wa.y, wa.z, wa.w, wb.x, wb.y, wb.z, wb.w};
                    #pragma unroll
                    for (int i = 0; i < 8; ++i)
                        #pragma unroll
                        for (int j = 0; j < 4; ++j)
                            acc[i][j] = fmaf(wv[i], xv[j + kx], acc[i][j]);
                }
            }
        }
    }

    #pragma unroll
    for (int i = 0; i < 8; ++i) {
        const int co = co0 + i;
        const float bv = (co < COA_) ? bias[co] : 0.f;
        float4 v;
        v.x = acc[i][0] + bv;
        v.y = acc[i][1] + bv;
        v.z = acc[i][2] + bv;
        v.w = acc[i][3] + bv;
        *reinterpret_cast<float4*>(&out[((size_t)b * CO_ + co) * HW_ + y * W_ + px0]) = v;
        float s = v.x + v.y + v.z + v.w;
        float q = v.x * v.x + v.y * v.y + v.z * v.z + v.w * v.w;
        #pragma unroll
        for (int m = 1; m < 32; m <<= 1) {   // reduce across the 32 lanes sharing cgi
            s += __shfl_xor(s, m);
            q += __shfl_xor(q, m);
        }
        if (pg == 0) {
            atomicAdd(&sums[co], s);
            atomicAdd(&sums[64 + co], q);
        }
    }
}

// ---------------------------------------------------------------------------
// sums[set][2][64] -> murs[set][2][64] = {mu, rsqrt(var+eps)}
// ---------------------------------------------------------------------------
__global__ void finalize_stats(const float* __restrict__ sums, float* __restrict__ murs)
{
    int set = blockIdx.x, c = threadIdx.x;
    const float invN = 1.f / (16.f * 16384.f);
    float s = sums[set * 128 + c];
    float q = sums[set * 128 + 64 + c];
    float mu = s * invN;
    float var = q * invN - mu * mu;
    murs[set * 128 + c] = mu;
    murs[set * 128 + 64 + c] = rsqrtf(fmaxf(var, 0.f) + 1e-5f);
}

// ---------------------------------------------------------------------------
// h = project(relu(BN(s)))  — builds conv2's 64-channel input.
// ---------------------------------------------------------------------------
__global__ __launch_bounds__(256) void bn_relu_project(
    const float* __restrict__ s, const float* __restrict__ murs,
    const float* __restrict__ g, const float* __restrict__ bt,
    float* __restrict__ h)
{
    int p = blockIdx.x * 256 + threadIdx.x;
    int b = p >> 14, rem = p & 16383;
    const float* sb = s + (size_t)b * CO_ * HW_ + rem;
    float* hb = h + (size_t)b * CO_ * HW_ + rem;
    float ssq = 0.f;
    for (int c = 0; c < COA_; ++c) {
        float v = sb[(size_t)c * HW_];
        v = g[c] * ((v - murs[c]) * murs[64 + c]) + bt[c];
        v = fmaxf(v, 0.f);
        ssq = fmaf(v, v, ssq);
        hb[(size_t)(c + 1) * HW_] = v;
    }
    hb[0] = sqrtf(1.f + ssq);
}

// ---------------------------------------------------------------------------
// out = project(relu(BN(s2) + BN(sp)))
// ---------------------------------------------------------------------------
__global__ __launch_bounds__(256) void residual_bn_relu_project(
    const float* __restrict__ s2, const float* __restrict__ sp,
    const float* __restrict__ murs2, const float* __restrict__ mursp,
    const float* __restrict__ g2, const float* __restrict__ bt2,
    const float* __restrict__ gp, const float* __restrict__ btp,
    float* __restrict__ out)
{
    int p = blockIdx.x * 256 + threadIdx.x;
    int b = p >> 14, rem = p & 16383;
    const float* s2b = s2 + (size_t)b * CO_ * HW_ + rem;
    const float* spb = sp + (size_t)b * CO_ * HW_ + rem;
    float* ob = out + (size_t)b * CO_ * HW_ + rem;
    float ssq = 0.f;
    for (int c = 0; c < COA_; ++c) {
        float v2 = s2b[(size_t)c * HW_];
        v2 = g2[c] * ((v2 - murs2[c]) * murs2[64 + c]) + bt2[c];
        float vp = spb[(size_t)c * HW_];
        vp = gp[c] * ((vp - mursp[c]) * mursp[64 + c]) + btp[c];
        float r = fmaxf(v2 + vp, 0.f);
        ssq = fmaf(r, r, ssq);
        ob[(size_t)(c + 1) * HW_] = r;
    }
    ob[0] = sqrtf(1.f + ssq);
}

// ---------------------------------------------------------------------------
extern "C" void kernel_launch(void* const* d_in, const int* in_sizes, int n_in,
                              void* d_out, int out_size, void* d_ws, size_t ws_size,
                              hipStream_t stream)
{
    (void)in_sizes; (void)n_in; (void)out_size; (void)ws_size;
    const float* x   = (const float*)d_in[0];
    const float* w1  = (const float*)d_in[1];
    const float* b1  = (const float*)d_in[2];
    const float* g1  = (const float*)d_in[3];
    const float* bt1 = (const float*)d_in[4];
    const float* w2  = (const float*)d_in[5];
    const float* b2  = (const float*)d_in[6];
    const float* g2  = (const float*)d_in[7];
    const float* bt2 = (const float*)d_in[8];
    const float* wp  = (const float*)d_in[9];
    const float* bp  = (const float*)d_in[10];
    const float* gp  = (const float*)d_in[11];
    const float* btp = (const float*)d_in[12];
    float* out = (float*)d_out;
    float* ws  = (float*)d_ws;

    // ws layout (floats): s1 (later reused as sp) | s2 | sums[3][128] | murs[3][128] | w1t | w2t | wpt
    float* s1   = ws;                       // 16,777,216
    float* s2   = ws + 16777216;            // 16,777,216
    float* sums = ws + 33554432;            // 384
    float* murs = sums + 384;               // 384
    float* w1t  = murs + 384;               // 18432
    float* w2t  = w1t + 18432;              // 36864
    float* wpt  = w2t + 36864;              // 2048

    hipMemsetAsync(sums, 0, 384 * sizeof(float), stream);
    prep_weights<<<72, 256, 0, stream>>>(w1, w1t, 32, 3);
    prep_weights<<<144, 256, 0, stream>>>(w2, w2t, 64, 3);
    prep_weights<<<8, 256, 0, stream>>>(wp, wpt, 32, 1);

    // conv1 -> s1 (+stats set 0)
    conv_bnstat<32, 3, 1><<<2048, 256, 0, stream>>>(x, w1t, b1, s1, sums);
    finalize_stats<<<1, 64, 0, stream>>>(sums, murs);
    // h = project(relu(BN(s1)))  -> stored in d_out (free scratch until final write)
    bn_relu_project<<<1024, 256, 0, stream>>>(s1, murs, g1, bt1, out);
    // conv2(h) -> s2 (+stats set 1)
    conv_bnstat<64, 3, 1><<<2048, 256, 0, stream>>>(out, w2t, b2, s2, sums + 128);
    // 1x1 projection conv(x) -> sp (reuses s1 buffer; s1 fully consumed) (+stats set 2)
    conv_bnstat<32, 1, 0><<<2048, 256, 0, stream>>>(x, wpt, bp, s1, sums + 256);
    finalize_stats<<<2, 64, 0, stream>>>(sums + 128, murs + 128);
    // out = project(relu(BN(s2) + BN(sp)))
    residual_bn_relu_project<<<1024, 256, 0, stream>>>(s2, s1, murs + 128, murs + 256,
                                                       g2, bt2, gp, btp, out);
}

// Round 9
// 807.789 us; speedup vs baseline: 1.9218x; 1.9218x over previous
//
#include <hip/hip_runtime.h>
#include <hip/hip_bf16.h>

#define H_ 128
#define W_ 128
#define HW_ 16384
#define B_ 16

using short8 = __attribute__((ext_vector_type(8))) short;
using f32x4  = __attribute__((ext_vector_type(4))) float;

__device__ __forceinline__ unsigned short f2b(float v) {
    __hip_bfloat16 h = __float2bfloat16(v);
    return *reinterpret_cast<unsigned short*>(&h);
}
__device__ __forceinline__ float b2f(unsigned short u) {
    __hip_bfloat16 h = *reinterpret_cast<__hip_bfloat16*>(&u);
    return __bfloat162float(h);
}

// ---------------------------------------------------------------------------
// x [B][32][H][W] f32  ->  xc [B][H][W][32] bf16
// ---------------------------------------------------------------------------
__global__ __launch_bounds__(256) void to_nhwc(
    const float* __restrict__ x, unsigned short* __restrict__ xc)
{
    int p = blockIdx.x * 256 + threadIdx.x;           // 0 .. B*HW-1
    int b = p >> 14, rem = p & 16383;
    const float* src = x + (size_t)b * 32 * HW_ + rem;
    unsigned short ob[32];
    #pragma unroll
    for (int c = 0; c < 32; ++c) ob[c] = f2b(src[(size_t)c * HW_]);
    unsigned short* dst = xc + (size_t)p * 32;
    #pragma unroll
    for (int k = 0; k < 4; ++k)
        *reinterpret_cast<short8*>(dst + k * 8) = *reinterpret_cast<short8*>(&ob[k * 8]);
}

// ---------------------------------------------------------------------------
// w [co<63][CIN][KS][KS] f32 -> wt [tap][cb][kb(4)][co(64)][j(8)] bf16
// ci = cb*32 + kb*8 + j ; tap = ky*KS + kx ; co=63 zero-padded.
// ---------------------------------------------------------------------------
__global__ __launch_bounds__(256) void prep_w(
    const float* __restrict__ w, unsigned short* __restrict__ wt, int CIN, int KS)
{
    int NCB = CIN >> 5;
    int total = KS * KS * NCB * 4 * 64 * 8;
    for (int i = blockIdx.x * 256 + threadIdx.x; i < total; i += gridDim.x * 256) {
        int j  = i & 7;
        int co = (i >> 3) & 63;
        int kb = (i >> 9) & 3;
        int cb = (i >> 11) % NCB;
        int tap = (i >> 11) / NCB;
        int ky = tap / KS, kx = tap % KS;
        int ci = cb * 32 + kb * 8 + j;
        float v = (co < 63) ? w[((co * CIN + ci) * KS + ky) * KS + kx] : 0.f;
        wt[i] = f2b(v);
    }
}

// ---------------------------------------------------------------------------
// Implicit-GEMM conv, one block per (b, y): 128 px x 64 co via 16x16x32 bf16
// MFMA. 4 waves, each 32 px x 64 co (A-frag reuse 1:4 vs MFMA).
// LDS A-tile padded to CIN/8+1 16B-chunks per x-position: pos stride =
// CIN*2+16 bytes; A-frag read byte ≡ ((pos+q)*16) mod 128 is uniform over
// the wave (8 lanes per 16B slot) -> ds_read_b128 BW floor, no conflicts.
// A = activations [pos][ci] (LDS), B = weights (global, coalesced 16B frags).
// Fused BN stats (per-co sum/sumsq) via shfl-reduce + atomics.
// MFMA mapping (m89/m91): A lane l -> row l&15, k-oct l>>4; B lane l ->
// col l&15, k-oct l>>4; D lane l -> col l&15, row 4*(l>>4)+reg.
// ---------------------------------------------------------------------------
template<int CIN, int KS, int PAD>
__global__ __launch_bounds__(256) void conv_mfma(
    const unsigned short* __restrict__ in,   // NHWC bf16 [B][H][W][CIN]
    const unsigned short* __restrict__ wt,   // packed weights
    unsigned short* __restrict__ outp,       // NHWC bf16 [B][H][W][64]
    float* __restrict__ sums)                // [0..63]=sum, [64..127]=sumsq
{
    constexpr int NCB = CIN / 32;
    constexpr int XCOLS = W_ + 2 * PAD;
    constexpr int TAPS = KS * KS;
    constexpr int C8  = CIN / 8;       // 16B chunks of real data per position
    constexpr int CPP = C8 + 1;        // +1 pad chunk per position
    __shared__ short8 xs[KS * XCOLS * CPP];

    const int b = blockIdx.x >> 7;
    const int y = blockIdx.x & 127;
    const int t = threadIdx.x;
    const int lane = t & 63;
    const int wv = t >> 6;
    const int pxbase = wv * 32;
    const int l15 = lane & 15;
    const int q = lane >> 4;

    // ---- stage KS input rows once (16B chunks, padded dest) ----
    constexpr int ROWCH = W_ * C8;
    for (int r = 0; r < KS; ++r) {
        const int yy = y + r - PAD;
        if (yy >= 0 && yy < H_) {
            const short8* src = reinterpret_cast<const short8*>(
                in + ((size_t)(b * H_ + yy) * W_) * CIN);
            for (int i = t; i < ROWCH; i += 256) {
                int pos = i / C8, slot = i % C8;
                xs[(r * XCOLS + PAD + pos) * CPP + slot] = src[i];
            }
        } else {
            short8 z = {};
            for (int i = t; i < ROWCH; i += 256) {
                int pos = i / C8, slot = i % C8;
                xs[(r * XCOLS + PAD + pos) * CPP + slot] = z;
            }
        }
    }
    if constexpr (PAD) {  // halo columns pos=0 and pos=XCOLS-1
        short8 z = {};
        for (int i = t; i < KS * 2 * C8; i += 256) {
            int r = i / (2 * C8);
            int rest = i % (2 * C8);
            int pos = (rest / C8) ? (XCOLS - 1) : 0;
            int slot = rest % C8;
            xs[(r * XCOLS + pos) * CPP + slot] = z;
        }
    }
    __syncthreads();

    f32x4 acc[2][4];                       // [f(16px)][cf(16co)]
    #pragma unroll
    for (int f = 0; f < 2; ++f)
        #pragma unroll
        for (int cf = 0; cf < 4; ++cf)
            #pragma unroll
            for (int r = 0; r < 4; ++r) acc[f][cf][r] = 0.f;

    const short8* wt8 = reinterpret_cast<const short8*>(wt);
    #pragma unroll
    for (int tap = 0; tap < TAPS; ++tap) {
        const int ky = tap / KS, kx = tap % KS;
        #pragma unroll
        for (int cb = 0; cb < NCB; ++cb) {
            // B frags: lane -> co = cf*16 + l15, k-oct q (coalesced 16B)
            const short8* wb = wt8 + (size_t)((tap * NCB + cb) * 4 + q) * 64;
            short8 bf[4];
            #pragma unroll
            for (int cf = 0; cf < 4; ++cf) bf[cf] = wb[cf * 16 + l15];
            #pragma unroll
            for (int f = 0; f < 2; ++f) {
                const int pos = pxbase + f * 16 + l15 + kx;   // input col + PAD
                short8 af = xs[(ky * XCOLS + pos) * CPP + cb * 4 + q];
                #pragma unroll
                for (int cf = 0; cf < 4; ++cf)
                    acc[f][cf] = __builtin_amdgcn_mfma_f32_16x16x32_bf16(
                        af, bf[cf], acc[f][cf], 0, 0, 0);
            }
        }
    }

    // ---- store (bf16 NHWC) + BN partial stats ----
    float sacc[4] = {0.f, 0.f, 0.f, 0.f}, qacc[4] = {0.f, 0.f, 0.f, 0.f};
    const size_t obase = ((size_t)(b * H_ + y) * W_) * 64;
    #pragma unroll
    for (int f = 0; f < 2; ++f)
        #pragma unroll
        for (int cf = 0; cf < 4; ++cf)
            #pragma unroll
            for (int r = 0; r < 4; ++r) {
                float v = acc[f][cf][r];
                int px = pxbase + f * 16 + q * 4 + r;
                int co = cf * 16 + l15;
                outp[obase + (size_t)px * 64 + co] = f2b(v);
                sacc[cf] += v;
                qacc[cf] = fmaf(v, v, qacc[cf]);
            }
    #pragma unroll
    for (int cf = 0; cf < 4; ++cf) {
        float s = sacc[cf], qq = qacc[cf];
        s += __shfl_xor(s, 16); qq += __shfl_xor(qq, 16);
        s += __shfl_xor(s, 32); qq += __shfl_xor(qq, 32);
        if (q == 0) {
            int co = cf * 16 + l15;
            atomicAdd(&sums[co], s);
            atomicAdd(&sums[64 + co], qq);
        }
    }
}

// ---------------------------------------------------------------------------
__global__ void finalize_stats(const float* __restrict__ sums, float* __restrict__ murs)
{
    int set = blockIdx.x, c = threadIdx.x;
    const float invN = 1.f / (16.f * 16384.f);
    float s = sums[set * 128 + c];
    float qv = sums[set * 128 + 64 + c];
    float mu = s * invN;
    float var = qv * invN - mu * mu;
    murs[set * 128 + c] = mu;
    murs[set * 128 + 64 + c] = rsqrtf(fmaxf(var, 0.f) + 1e-5f);
}

// ---------------------------------------------------------------------------
// h = project(relu(BN(s1)))  NHWC bf16 (ch0 = time)
// ---------------------------------------------------------------------------
__global__ __launch_bounds__(256) void epi1(
    const unsigned short* __restrict__ s1, const float* __restrict__ murs,
    const float* __restrict__ g, const float* __restrict__ bt,
    unsigned short* __restrict__ h)
{
    int p = blockIdx.x * 256 + threadIdx.x;
    const unsigned short* sp = s1 + (size_t)p * 64;
    unsigned short ib[64], ob[64];
    #pragma unroll
    for (int k = 0; k < 8; ++k)
        *reinterpret_cast<short8*>(&ib[k * 8]) = *reinterpret_cast<const short8*>(sp + k * 8);
    float ssq = 0.f;
    #pragma unroll
    for (int c = 0; c < 63; ++c) {
        float v = b2f(ib[c]);
        v = g[c] * ((v - murs[c]) * murs[64 + c]) + bt[c];
        v = fmaxf(v, 0.f);
        ssq = fmaf(v, v, ssq);
        ob[c + 1] = f2b(v);
    }
    ob[0] = f2b(sqrtf(1.f + ssq));
    unsigned short* hp = h + (size_t)p * 64;
    #pragma unroll
    for (int k = 0; k < 8; ++k)
        *reinterpret_cast<short8*>(hp + k * 8) = *reinterpret_cast<short8*>(&ob[k * 8]);
}

// ---------------------------------------------------------------------------
// out = project(relu(BN(s2) + BN(sp)))  -> f32 NCHW (ch0 = time)
// ---------------------------------------------------------------------------
__global__ __launch_bounds__(256) void epi2(
    const unsigned short* __restrict__ s2, const unsigned short* __restrict__ spb,
    const float* __restrict__ murs2, const float* __restrict__ mursp,
    const float* __restrict__ g2, const float* __restrict__ bt2,
    const float* __restrict__ gp, const float* __restrict__ btp,
    float* __restrict__ out)
{
    int p = blockIdx.x * 256 + threadIdx.x;
    int b = p >> 14, rem = p & 16383;
    unsigned short i2[64], ip[64];
    #pragma unroll
    for (int k = 0; k < 8; ++k) {
        *reinterpret_cast<short8*>(&i2[k * 8]) =
            *reinterpret_cast<const short8*>(s2 + (size_t)p * 64 + k * 8);
        *reinterpret_cast<short8*>(&ip[k * 8]) =
            *reinterpret_cast<const short8*>(spb + (size_t)p * 64 + k * 8);
    }
    float* ob = out + (size_t)b * 64 * HW_ + rem;
    float ssq = 0.f;
    #pragma unroll
    for (int c = 0; c < 63; ++c) {
        float v2 = b2f(i2[c]);
        v2 = g2[c] * ((v2 - murs2[c]) * murs2[64 + c]) + bt2[c];
        float vp = b2f(ip[c]);
        vp = gp[c] * ((vp - mursp[c]) * mursp[64 + c]) + btp[c];
        float r = fmaxf(v2 + vp, 0.f);
        ssq = fmaf(r, r, ssq);
        ob[(size_t)(c + 1) * HW_] = r;
    }
    ob[0] = sqrtf(1.f + ssq);
}

// ---------------------------------------------------------------------------
extern "C" void kernel_launch(void* const* d_in, const int* in_sizes, int n_in,
                              void* d_out, int out_size, void* d_ws, size_t ws_size,
                              hipStream_t stream)
{
    (void)in_sizes; (void)n_in; (void)out_size; (void)ws_size;
    const float* x   = (const float*)d_in[0];
    const float* w1  = (const float*)d_in[1];
    const float* g1  = (const float*)d_in[3];
    const float* bt1 = (const float*)d_in[4];
    const float* w2  = (const float*)d_in[5];
    const float* g2  = (const float*)d_in[7];
    const float* bt2 = (const float*)d_in[8];
    const float* wp  = (const float*)d_in[9];
    const float* gp  = (const float*)d_in[11];
    const float* btp = (const float*)d_in[12];
    // biases b1/b2/bp are mathematically dead: BN immediately follows each conv.
    float* out = (float*)d_out;
    char* ws = (char*)d_ws;

    // ws layout (bytes)
    unsigned short* xc  = (unsigned short*)(ws);                 // 16,777,216 B
    unsigned short* s1  = (unsigned short*)(ws + 16777216);      // 33,554,432 B (reused as sp)
    unsigned short* h   = (unsigned short*)(ws + 50331648);      // 33,554,432 B
    unsigned short* s2  = (unsigned short*)(ws + 83886080);      // 33,554,432 B
    unsigned short* w1t = (unsigned short*)(ws + 117440512);     //     36,864 B
    unsigned short* w2t = (unsigned short*)(ws + 117477376);     //     73,728 B
    unsigned short* wpt = (unsigned short*)(ws + 117551104);     //      4,096 B
    float* sums = (float*)(ws + 117555200);                      //      1,536 B
    float* murs = (float*)(ws + 117556736);                      //      1,536 B

    hipMemsetAsync(sums, 0, 1536, stream);
    to_nhwc<<<1024, 256, 0, stream>>>(x, xc);
    prep_w<<<72, 256, 0, stream>>>(w1, w1t, 32, 3);
    prep_w<<<144, 256, 0, stream>>>(w2, w2t, 64, 3);
    prep_w<<<8, 256, 0, stream>>>(wp, wpt, 32, 1);

    conv_mfma<32, 3, 1><<<2048, 256, 0, stream>>>(xc, w1t, s1, sums);
    finalize_stats<<<1, 64, 0, stream>>>(sums, murs);
    epi1<<<1024, 256, 0, stream>>>(s1, murs, g1, bt1, h);
    conv_mfma<64, 3, 1><<<2048, 256, 0, stream>>>(h, w2t, s2, sums + 128);
    conv_mfma<32, 1, 0><<<2048, 256, 0, stream>>>(xc, wpt, s1, sums + 256);  // sp reuses s1
    finalize_stats<<<2, 64, 0, stream>>>(sums + 128, murs + 128);
    epi2<<<1024, 256, 0, stream>>>(s2, s1, murs + 128, murs + 256,
                                   g2, bt2, gp, btp, out);
}

// Round 10
// 502.899 us; speedup vs baseline: 3.0869x; 1.6063x over previous
//
#include <hip/hip_runtime.h>
#include <hip/hip_bf16.h>

#define H_ 128
#define W_ 128
#define HW_ 16384
#define B_ 16

using short8 = __attribute__((ext_vector_type(8))) short;
using f32x4  = __attribute__((ext_vector_type(4))) float;

__device__ __forceinline__ unsigned short f2b(float v) {
    __hip_bfloat16 h = __float2bfloat16(v);
    return *reinterpret_cast<unsigned short*>(&h);
}
__device__ __forceinline__ float b2f(unsigned short u) {
    __hip_bfloat16 h = *reinterpret_cast<__hip_bfloat16*>(&u);
    return __bfloat162float(h);
}

// ---------------------------------------------------------------------------
// x [B][32][H][W] f32  ->  xc [B][H][W][32] bf16
// ---------------------------------------------------------------------------
__global__ __launch_bounds__(256) void to_nhwc(
    const float* __restrict__ x, unsigned short* __restrict__ xc)
{
    int p = blockIdx.x * 256 + threadIdx.x;           // 0 .. B*HW-1
    int b = p >> 14, rem = p & 16383;
    const float* src = x + (size_t)b * 32 * HW_ + rem;
    unsigned short ob[32];
    #pragma unroll
    for (int c = 0; c < 32; ++c) ob[c] = f2b(src[(size_t)c * HW_]);
    unsigned short* dst = xc + (size_t)p * 32;
    #pragma unroll
    for (int k = 0; k < 4; ++k)
        *reinterpret_cast<short8*>(dst + k * 8) = *reinterpret_cast<short8*>(&ob[k * 8]);
}

// ---------------------------------------------------------------------------
// w [co<63][CIN][KS][KS] f32 -> wt [tap][cb][kb(4)][co(64)][j(8)] bf16
// ci = cb*32 + kb*8 + j ; tap = ky*KS + kx ; co=63 zero-padded.
// ---------------------------------------------------------------------------
__global__ __launch_bounds__(256) void prep_w(
    const float* __restrict__ w, unsigned short* __restrict__ wt, int CIN, int KS)
{
    int NCB = CIN >> 5;
    int total = KS * KS * NCB * 4 * 64 * 8;
    for (int i = blockIdx.x * 256 + threadIdx.x; i < total; i += gridDim.x * 256) {
        int j  = i & 7;
        int co = (i >> 3) & 63;
        int kb = (i >> 9) & 3;
        int cb = (i >> 11) % NCB;
        int tap = (i >> 11) / NCB;
        int ky = tap / KS, kx = tap % KS;
        int ci = cb * 32 + kb * 8 + j;
        float v = (co < 63) ? w[((co * CIN + ci) * KS + ky) * KS + kx] : 0.f;
        wt[i] = f2b(v);
    }
}

// ---------------------------------------------------------------------------
// Implicit-GEMM conv, one block per (b, y): 128 px x 64 co via 16x16x32 bf16
// MFMA. 4 waves, each 64 px x 32 co: wv>>1 = px half, wv&1 = co half.
// ALL weight B-fragments are preloaded into VGPRs before the K-loop (round-9
// counters showed per-iter global B loads serialized the loop at ~900 cyc/iter
// with MfmaUtil 3.4%): inner loop is pure LDS + MFMA.
// LDS A-tile padded to CIN/8+1 16B-chunks per x-position -> A-frag read byte
// ≡ (pos+const)*16 mod 128, uniform over the wave (8 lanes/slot): conflict-free.
// MFMA mapping (m89/m91): A lane l -> row l&15, k-oct l>>4; B lane l ->
// col l&15, k-oct l>>4; D lane l -> col l&15, row 4*(l>>4)+reg.
// ---------------------------------------------------------------------------
template<int CIN, int KS, int PAD>
__global__ __launch_bounds__(256) void conv_mfma(
    const unsigned short* __restrict__ in,   // NHWC bf16 [B][H][W][CIN]
    const unsigned short* __restrict__ wt,   // packed weights
    unsigned short* __restrict__ outp,       // NHWC bf16 [B][H][W][64]
    float* __restrict__ sums)                // [0..63]=sum, [64..127]=sumsq
{
    constexpr int NCB = CIN / 32;
    constexpr int XCOLS = W_ + 2 * PAD;
    constexpr int TAPS = KS * KS;
    constexpr int NK  = TAPS * NCB;    // total K-iterations
    constexpr int C8  = CIN / 8;       // 16B chunks of real data per position
    constexpr int CPP = C8 + 1;        // +1 pad chunk per position
    __shared__ short8 xs[KS * XCOLS * CPP];

    const int b = blockIdx.x >> 7;
    const int y = blockIdx.x & 127;
    const int t = threadIdx.x;
    const int lane = t & 63;
    const int wv = t >> 6;
    const int pxbase = (wv >> 1) * 64;
    const int cobase = (wv & 1) * 32;
    const int l15 = lane & 15;
    const int q = lane >> 4;

    // ---- preload ALL B-fragments into registers (one burst, no loop-carried
    //      global latency). conv2: 36 frags = 144 VGPR; conv1: 18; 1x1: 2. ----
    const short8* wt8 = reinterpret_cast<const short8*>(wt);
    short8 bf[NK][2];
    #pragma unroll
    for (int tc = 0; tc < NK; ++tc)
        #pragma unroll
        for (int cf = 0; cf < 2; ++cf)
            bf[tc][cf] = wt8[(size_t)(tc * 4 + q) * 64 + cobase + cf * 16 + l15];

    // ---- stage KS input rows once (16B chunks, padded dest) ----
    constexpr int ROWCH = W_ * C8;
    for (int r = 0; r < KS; ++r) {
        const int yy = y + r - PAD;
        if (yy >= 0 && yy < H_) {
            const short8* src = reinterpret_cast<const short8*>(
                in + ((size_t)(b * H_ + yy) * W_) * CIN);
            for (int i = t; i < ROWCH; i += 256) {
                int pos = i / C8, slot = i % C8;
                xs[(r * XCOLS + PAD + pos) * CPP + slot] = src[i];
            }
        } else {
            short8 z = {};
            for (int i = t; i < ROWCH; i += 256) {
                int pos = i / C8, slot = i % C8;
                xs[(r * XCOLS + PAD + pos) * CPP + slot] = z;
            }
        }
    }
    if constexpr (PAD) {  // halo columns pos=0 and pos=XCOLS-1
        short8 z = {};
        for (int i = t; i < KS * 2 * C8; i += 256) {
            int r = i / (2 * C8);
            int rest = i % (2 * C8);
            int pos = (rest / C8) ? (XCOLS - 1) : 0;
            int slot = rest % C8;
            xs[(r * XCOLS + pos) * CPP + slot] = z;
        }
    }
    __syncthreads();

    f32x4 acc[4][2];                       // [f(16px)][cf(16co)]
    #pragma unroll
    for (int f = 0; f < 4; ++f)
        #pragma unroll
        for (int cf = 0; cf < 2; ++cf)
            #pragma unroll
            for (int r = 0; r < 4; ++r) acc[f][cf][r] = 0.f;

    #pragma unroll
    for (int tap = 0; tap < TAPS; ++tap) {
        const int ky = tap / KS, kx = tap % KS;
        #pragma unroll
        for (int cb = 0; cb < NCB; ++cb) {
            short8 af[4];
            #pragma unroll
            for (int f = 0; f < 4; ++f) {
                const int pos = pxbase + f * 16 + l15 + kx;   // input col + PAD
                af[f] = xs[(ky * XCOLS + pos) * CPP + cb * 4 + q];
            }
            #pragma unroll
            for (int f = 0; f < 4; ++f)
                #pragma unroll
                for (int cf = 0; cf < 2; ++cf)
                    acc[f][cf] = __builtin_amdgcn_mfma_f32_16x16x32_bf16(
                        af[f], bf[tap * NCB + cb][cf], acc[f][cf], 0, 0, 0);
        }
    }

    // ---- store (bf16 NHWC) + BN partial stats ----
    float sacc[2] = {0.f, 0.f}, qacc[2] = {0.f, 0.f};
    const size_t obase = ((size_t)(b * H_ + y) * W_) * 64;
    #pragma unroll
    for (int f = 0; f < 4; ++f)
        #pragma unroll
        for (int cf = 0; cf < 2; ++cf)
            #pragma unroll
            for (int r = 0; r < 4; ++r) {
                float v = acc[f][cf][r];
                int px = pxbase + f * 16 + q * 4 + r;
                int co = cobase + cf * 16 + l15;
                outp[obase + (size_t)px * 64 + co] = f2b(v);
                sacc[cf] += v;
                qacc[cf] = fmaf(v, v, qacc[cf]);
            }
    #pragma unroll
    for (int cf = 0; cf < 2; ++cf) {
        float s = sacc[cf], qq = qacc[cf];
        s += __shfl_xor(s, 16); qq += __shfl_xor(qq, 16);
        s += __shfl_xor(s, 32); qq += __shfl_xor(qq, 32);
        if (q == 0) {
            int co = cobase + cf * 16 + l15;
            atomicAdd(&sums[co], s);
            atomicAdd(&sums[64 + co], qq);
        }
    }
}

// ---------------------------------------------------------------------------
__global__ void finalize_stats(const float* __restrict__ sums, float* __restrict__ murs)
{
    int set = blockIdx.x, c = threadIdx.x;
    const float invN = 1.f / (16.f * 16384.f);
    float s = sums[set * 128 + c];
    float qv = sums[set * 128 + 64 + c];
    float mu = s * invN;
    float var = qv * invN - mu * mu;
    murs[set * 128 + c] = mu;
    murs[set * 128 + 64 + c] = rsqrtf(fmaxf(var, 0.f) + 1e-5f);
}

// ---------------------------------------------------------------------------
// h = project(relu(BN(s1)))  NHWC bf16 (ch0 = time)
// ---------------------------------------------------------------------------
__global__ __launch_bounds__(256) void epi1(
    const unsigned short* __restrict__ s1, const float* __restrict__ murs,
    const float* __restrict__ g, const float* __restrict__ bt,
    unsigned short* __restrict__ h)
{
    int p = blockIdx.x * 256 + threadIdx.x;
    const unsigned short* sp = s1 + (size_t)p * 64;
    unsigned short ib[64], ob[64];
    #pragma unroll
    for (int k = 0; k < 8; ++k)
        *reinterpret_cast<short8*>(&ib[k * 8]) = *reinterpret_cast<const short8*>(sp + k * 8);
    float ssq = 0.f;
    #pragma unroll
    for (int c = 0; c < 63; ++c) {
        float v = b2f(ib[c]);
        v = g[c] * ((v - murs[c]) * murs[64 + c]) + bt[c];
        v = fmaxf(v, 0.f);
        ssq = fmaf(v, v, ssq);
        ob[c + 1] = f2b(v);
    }
    ob[0] = f2b(sqrtf(1.f + ssq));
    unsigned short* hp = h + (size_t)p * 64;
    #pragma unroll
    for (int k = 0; k < 8; ++k)
        *reinterpret_cast<short8*>(hp + k * 8) = *reinterpret_cast<short8*>(&ob[k * 8]);
}

// ---------------------------------------------------------------------------
// out = project(relu(BN(s2) + BN(sp)))  -> f32 NCHW (ch0 = time)
// ---------------------------------------------------------------------------
__global__ __launch_bounds__(256) void epi2(
    const unsigned short* __restrict__ s2, const unsigned short* __restrict__ spb,
    const float* __restrict__ murs2, const float* __restrict__ mursp,
    const float* __restrict__ g2, const float* __restrict__ bt2,
    const float* __restrict__ gp, const float* __restrict__ btp,
    float* __restrict__ out)
{
    int p = blockIdx.x * 256 + threadIdx.x;
    int b = p >> 14, rem = p & 16383;
    unsigned short i2[64], ip[64];
    #pragma unroll
    for (int k = 0; k < 8; ++k) {
        *reinterpret_cast<short8*>(&i2[k * 8]) =
            *reinterpret_cast<const short8*>(s2 + (size_t)p * 64 + k * 8);
        *reinterpret_cast<short8*>(&ip[k * 8]) =
            *reinterpret_cast<const short8*>(spb + (size_t)p * 64 + k * 8);
    }
    float* ob = out + (size_t)b * 64 * HW_ + rem;
    float ssq = 0.f;
    #pragma unroll
    for (int c = 0; c < 63; ++c) {
        float v2 = b2f(i2[c]);
        v2 = g2[c] * ((v2 - murs2[c]) * murs2[64 + c]) + bt2[c];
        float vp = b2f(ip[c]);
        vp = gp[c] * ((vp - mursp[c]) * mursp[64 + c]) + btp[c];
        float r = fmaxf(v2 + vp, 0.f);
        ssq = fmaf(r, r, ssq);
        ob[(size_t)(c + 1) * HW_] = r;
    }
    ob[0] = sqrtf(1.f + ssq);
}

// ---------------------------------------------------------------------------
extern "C" void kernel_launch(void* const* d_in, const int* in_sizes, int n_in,
                              void* d_out, int out_size, void* d_ws, size_t ws_size,
                              hipStream_t stream)
{
    (void)in_sizes; (void)n_in; (void)out_size; (void)ws_size;
    const float* x   = (const float*)d_in[0];
    const float* w1  = (const float*)d_in[1];
    const float* g1  = (const float*)d_in[3];
    const float* bt1 = (const float*)d_in[4];
    const float* w2  = (const float*)d_in[5];
    const float* g2  = (const float*)d_in[7];
    const float* bt2 = (const float*)d_in[8];
    const float* wp  = (const float*)d_in[9];
    const float* gp  = (const float*)d_in[11];
    const float* btp = (const float*)d_in[12];
    // biases b1/b2/bp are mathematically dead: BN immediately follows each conv.
    float* out = (float*)d_out;
    char* ws = (char*)d_ws;

    // ws layout (bytes)
    unsigned short* xc  = (unsigned short*)(ws);                 // 16,777,216 B
    unsigned short* s1  = (unsigned short*)(ws + 16777216);      // 33,554,432 B (reused as sp)
    unsigned short* h   = (unsigned short*)(ws + 50331648);      // 33,554,432 B
    unsigned short* s2  = (unsigned short*)(ws + 83886080);      // 33,554,432 B
    unsigned short* w1t = (unsigned short*)(ws + 117440512);     //     36,864 B
    unsigned short* w2t = (unsigned short*)(ws + 117477376);     //     73,728 B
    unsigned short* wpt = (unsigned short*)(ws + 117551104);     //      4,096 B
    float* sums = (float*)(ws + 117555200);                      //      1,536 B
    float* murs = (float*)(ws + 117556736);                      //      1,536 B

    hipMemsetAsync(sums, 0, 1536, stream);
    to_nhwc<<<1024, 256, 0, stream>>>(x, xc);
    prep_w<<<72, 256, 0, stream>>>(w1, w1t, 32, 3);
    prep_w<<<144, 256, 0, stream>>>(w2, w2t, 64, 3);
    prep_w<<<8, 256, 0, stream>>>(wp, wpt, 32, 1);

    conv_mfma<32, 3, 1><<<2048, 256, 0, stream>>>(xc, w1t, s1, sums);
    finalize_stats<<<1, 64, 0, stream>>>(sums, murs);
    epi1<<<1024, 256, 0, stream>>>(s1, murs, g1, bt1, h);
    conv_mfma<64, 3, 1><<<2048, 256, 0, stream>>>(h, w2t, s2, sums + 128);
    conv_mfma<32, 1, 0><<<2048, 256, 0, stream>>>(xc, wpt, s1, sums + 256);  // sp reuses s1
    finalize_stats<<<2, 64, 0, stream>>>(sums + 128, murs + 128);
    epi2<<<1024, 256, 0, stream>>>(s2, s1, murs + 128, murs + 256,
                                   g2, bt2, gp, btp, out);
}